// Round 14
// baseline (660.308 us; speedup 1.0000x reference)
//
#include <hip/hip_runtime.h>

typedef _Float16 f16;
typedef _Float16 f16x2 __attribute__((ext_vector_type(2)));
typedef _Float16 f16x4 __attribute__((ext_vector_type(4)));
typedef _Float16 f16x8 __attribute__((ext_vector_type(8)));
typedef float    f32x4 __attribute__((ext_vector_type(4)));
typedef int      i32x4 __attribute__((ext_vector_type(4)));
typedef unsigned int u32x4 __attribute__((ext_vector_type(4)));

// ---------- helpers ----------
__device__ __forceinline__ float dot2u(unsigned a, unsigned b, float c){
  return __builtin_amdgcn_fdot2(__builtin_bit_cast(f16x2, a),
                                __builtin_bit_cast(f16x2, b), c, false);
}
__device__ __forceinline__ float sigm(float x){ return 1.0f/(1.0f+__expf(-x)); }
__device__ __forceinline__ float tanh_(float x){
  x = fminf(fmaxf(x, -20.f), 20.f);
  return 1.0f - 2.0f/(__expf(2.0f*x)+1.0f);
}
__device__ __forceinline__ float rdlane(float v, int idx){
  return __builtin_bit_cast(float,
           __builtin_amdgcn_readlane(__builtin_bit_cast(int, v), idx));
}

// Barrier that does NOT drain vmcnt (cross-thread traffic is LDS-only).
__device__ __forceinline__ void bar_lgkm(){
  asm volatile("s_waitcnt lgkmcnt(0)\n\ts_barrier" ::: "memory");
}
// Full barrier incl. vmcnt drain (for global_load_lds arrival).
__device__ __forceinline__ void bar_vm(){
  asm volatile("s_waitcnt vmcnt(0) lgkmcnt(0)\n\ts_barrier" ::: "memory");
}

#if __has_builtin(__builtin_amdgcn_global_load_lds)
#define HAVE_GLL 1
#else
#define HAVE_GLL 0
#endif

// ---------- K0b: fp32 -> i8 quantize (16 elems/thread), clamp +-127 ----------
__global__ void k_cvt8(const float* __restrict__ src, signed char* __restrict__ dst,
                       int n, float scale){
  int i = (blockIdx.x*256 + threadIdx.x)*16;
  if (i >= n) return;
  u32x4 o;
  #pragma unroll
  for (int q=0;q<4;q++){
    float4 a = *(const float4*)(src + i + q*4);
    int q0 = (int)rintf(a.x*scale); q0 = q0>127?127:(q0<-127?-127:q0);
    int q1 = (int)rintf(a.y*scale); q1 = q1>127?127:(q1<-127?-127:q1);
    int q2 = (int)rintf(a.z*scale); q2 = q2>127?127:(q2<-127?-127:q2);
    int q3 = (int)rintf(a.w*scale); q3 = q3>127?127:(q3<-127?-127:q3);
    o[q] = ((unsigned)(unsigned char)(signed char)q0)
         | (((unsigned)(unsigned char)(signed char)q1) << 8)
         | (((unsigned)(unsigned char)(signed char)q2) << 16)
         | (((unsigned)(unsigned char)(signed char)q3) << 24);
  }
  *(u32x4*)(dst+i) = o;
}

// ---------- K_prep: merged small prep (W8 quant f/b, Wpj cvt+pad, W_hh pack) ----------
// bid 0..191: quant wihf -> W8 ; 192..383: quant wihb -> W8+786432 ;
// 384..386: wprj fp32->f16 ; 387..514: wpack7.
__global__ void k_prep(const float* __restrict__ wihf, const float* __restrict__ wihb,
                       const float* __restrict__ wprj, const float* __restrict__ whf,
                       const float* __restrict__ whb, signed char* __restrict__ W8,
                       f16* __restrict__ Wpj, u32x4* __restrict__ wf){
  int bid = blockIdx.x, tid = threadIdx.x;
  if (bid < 384){
    const float* src = (bid < 192) ? wihf : wihb;
    signed char* dst = W8 + ((bid < 192) ? 0 : 786432);
    int b2 = (bid < 192) ? bid : bid - 192;
    int i = (b2*256 + tid)*16;
    if (i >= 786432) return;
    u32x4 o;
    #pragma unroll
    for (int q=0;q<4;q++){
      float4 a = *(const float4*)(src + i + q*4);
      int q0 = (int)rintf(a.x*2048.f); q0 = q0>127?127:(q0<-127?-127:q0);
      int q1 = (int)rintf(a.y*2048.f); q1 = q1>127?127:(q1<-127?-127:q1);
      int q2 = (int)rintf(a.z*2048.f); q2 = q2>127?127:(q2<-127?-127:q2);
      int q3 = (int)rintf(a.w*2048.f); q3 = q3>127?127:(q3<-127?-127:q3);
      o[q] = ((unsigned)(unsigned char)(signed char)q0)
           | (((unsigned)(unsigned char)(signed char)q1) << 8)
           | (((unsigned)(unsigned char)(signed char)q2) << 16)
           | (((unsigned)(unsigned char)(signed char)q3) << 24);
    }
    *(u32x4*)(dst+i) = o;
  } else if (bid < 387){
    int i = ((bid-384)*256 + tid)*8;
    if (i >= 4608) return;
    float4 a = *(const float4*)(wprj + i);
    float4 b = *(const float4*)(wprj + i + 4);
    f16x8 o;
    o[0]=(f16)a.x; o[1]=(f16)a.y; o[2]=(f16)a.z; o[3]=(f16)a.w;
    o[4]=(f16)b.x; o[5]=(f16)b.y; o[6]=(f16)b.z; o[7]=(f16)b.w;
    *(f16x8*)(Wpj+i) = o;
  } else {
    int idx = (bid-387)*256 + tid;    // 0..32767
    int lane = idx & 63;
    int kt   = (idx >> 6) & 3;
    int rt   = (idx >> 8) & 7;
    int wv   = (idx >> 11) & 7;
    int dir  = (idx >> 14) & 1;
    const float* w = dir ? whb : whf;
    int i2 = lane & 15;
    int u  = wv*32 + (i2 >> 2)*8 + rt;
    int g  = i2 & 3;
    int k0 = kt*64 + (lane >> 4)*16;
    const float* row = w + (size_t)(g*256 + u)*256 + k0;
    u32x4 v = {0,0,0,0};
    #pragma unroll
    for (int j=0;j<16;j++){
      int q = (int)rintf(row[j] * 2048.0f);
      q = q > 127 ? 127 : (q < -127 ? -127 : q);
      v[j>>2] |= ((unsigned)(unsigned char)(signed char)q) << ((j&3)*8);
    }
    wf[idx] = v;
  }
}

// ---------- K1: gx = X8 @ W8^T * 1/65536 + bias -> f16  (i8 MFMA 16x16x64) ----------
// T14-pipelined 2-phase: per iter {ds_read frags->regs | lgkm-bar | issue next
// STAGE (GLL) | 32 MFMAs from regs | vmcnt(0)+bar}. Stage latency hides under
// MFMA. Single 32KB LDS buffer (dbuf would halve occupancy — m132). T2
// XOR-swizzle both-sides (rule 21) kept from r12.
__global__ __launch_bounds__(256) void k_gemm8(const signed char* __restrict__ A8,
                                               const signed char* __restrict__ B8,
                                               const float* __restrict__ bf_,
                                               const float* __restrict__ bb_,
                                               f16* __restrict__ C){
  __shared__ alignas(16) signed char As[128][128];
  __shared__ alignas(16) signed char Bs[128][128];
  int bid = blockIdx.x;
  int bm = bid >> 4, bn = bid & 15;
  int tid = threadIdx.x;
  int w = tid >> 6, l = tid & 63;
  int wm = w >> 1, wn = w & 1;
  i32x4 acc[4][4] = {};
  const signed char* Agb = A8 + (size_t)(bm*128)*768;
  const signed char* Bgb = B8 + (size_t)(bn*128)*768;
  int fr = l & 15, kg = l >> 4;
  int swzA = (fr & 7) << 4;                      // read-side XOR for A/B frags
#if HAVE_GLL
  int colsw = ((l&7)*16) ^ (((l>>3)&7)<<4);      // source col pre-swizzled
  int rowl  = l >> 3;
  // prologue: stage tile 0, wait, sync
  #pragma unroll
  for (int i=0;i<4;i++){
    int row = (w*4+i)*8 + rowl;
    __builtin_amdgcn_global_load_lds(
      (const __attribute__((address_space(1))) void*)(Agb + (size_t)row*768 + 0 + colsw),
      (__attribute__((address_space(3))) void*)((char*)&As[0][0] + (w*4+i)*1024),
      16, 0, 0);
    __builtin_amdgcn_global_load_lds(
      (const __attribute__((address_space(1))) void*)(Bgb + (size_t)row*768 + 0 + colsw),
      (__attribute__((address_space(3))) void*)((char*)&Bs[0][0] + (w*4+i)*1024),
      16, 0, 0);
  }
  bar_vm();
  for (int it=0; it<6; ++it){
    // phase 1: LDS -> regs (all 16 frags)
    i32x4 af[2][4], bf[2][4];
    #pragma unroll
    for (int ks=0; ks<2; ks++){
      #pragma unroll
      for (int mi=0;mi<4;mi++)
        af[ks][mi] = *(const i32x4*)&As[wm*64+mi*16+fr][(ks*64+kg*16) ^ swzA];
      #pragma unroll
      for (int ni=0;ni<4;ni++)
        bf[ks][ni] = *(const i32x4*)&Bs[wn*64+ni*16+fr][(ks*64+kg*16) ^ swzA];
    }
    bar_lgkm();                         // all reads done -> buffer reusable
    // phase 2: issue next tile's stage (completion hidden under MFMA)
    if (it < 5){
      int k0n = (it+1)*128;
      #pragma unroll
      for (int i=0;i<4;i++){
        int row = (w*4+i)*8 + rowl;
        __builtin_amdgcn_global_load_lds(
          (const __attribute__((address_space(1))) void*)(Agb + (size_t)row*768 + k0n + colsw),
          (__attribute__((address_space(3))) void*)((char*)&As[0][0] + (w*4+i)*1024),
          16, 0, 0);
        __builtin_amdgcn_global_load_lds(
          (const __attribute__((address_space(1))) void*)(Bgb + (size_t)row*768 + k0n + colsw),
          (__attribute__((address_space(3))) void*)((char*)&Bs[0][0] + (w*4+i)*1024),
          16, 0, 0);
      }
    }
    // phase 3: MFMA from regs
    #pragma unroll
    for (int ks=0; ks<2; ks++)
      #pragma unroll
      for (int mi=0;mi<4;mi++)
        #pragma unroll
        for (int ni=0;ni<4;ni++)
          acc[mi][ni] = __builtin_amdgcn_mfma_i32_16x16x64_i8(af[ks][mi], bf[ks][ni], acc[mi][ni], 0,0,0);
    if (it < 5) bar_vm();               // staged tile landed for next iter
  }
#else
  int srow = tid >> 3;
  int scol = (tid & 7)*16;
  int swzW = (srow & 7) << 4;
  for (int k0 = 0; k0 < 768; k0 += 128){
    #pragma unroll
    for (int q=0;q<4;q++){
      int rr = srow + 32*q;
      u32x4 av = *(const u32x4*)(Agb + (size_t)rr*768 + k0 + scol);
      u32x4 bv = *(const u32x4*)(Bgb + (size_t)rr*768 + k0 + scol);
      *(u32x4*)&As[rr][scol ^ swzW] = av;
      *(u32x4*)&Bs[rr][scol ^ swzW] = bv;
    }
    __syncthreads();
    #pragma unroll
    for (int ks=0; ks<2; ks++){
      i32x4 af[4], bf[4];
      #pragma unroll
      for (int mi=0;mi<4;mi++)
        af[mi] = *(const i32x4*)&As[wm*64+mi*16+fr][(ks*64+kg*16) ^ swzA];
      #pragma unroll
      for (int ni=0;ni<4;ni++)
        bf[ni] = *(const i32x4*)&Bs[wn*64+ni*16+fr][(ks*64+kg*16) ^ swzA];
      #pragma unroll
      for (int mi=0;mi<4;mi++)
        #pragma unroll
        for (int ni=0;ni<4;ni++)
          acc[mi][ni] = __builtin_amdgcn_mfma_i32_16x16x64_i8(af[mi], bf[ni], acc[mi][ni], 0,0,0);
    }
    __syncthreads();
  }
#endif
  const float GS = 1.0f/65536.0f;      // 1/(scaleX * scaleW) = 1/(32*2048)
  int fq = l >> 4;
  #pragma unroll
  for (int ni=0;ni<4;ni++){
    int ncol = bn*128 + wn*64 + ni*16 + fr;
    float bv = (ncol < 1024) ? bf_[ncol] : bb_[ncol - 1024];
    #pragma unroll
    for (int mi=0;mi<4;mi++){
      int mrow = bm*128 + wm*64 + mi*16 + fq*4;
      #pragma unroll
      for (int r=0;r<4;r++)
        C[(size_t)(mrow+r)*2048 + ncol] = (f16)((float)acc[mi][ni][r]*GS + bv);
    }
  }
}

// ---------- K2: recurrence. 128 blocks (1 chain each), i8 MFMA 16x16x64 ----------
// (FROZEN — proven at ~521 us)
__global__ __launch_bounds__(512,2) void k_rnn(const i32x4* __restrict__ wfrag,
            const f16* __restrict__ gx, f16* __restrict__ Hc){
  __shared__ alignas(16) unsigned char lhB[2][256];
  int bid = blockIdx.x;                // 0..127
  int b = bid >> 1, dir = bid & 1;
  int tid = threadIdx.x;
  int wv = tid >> 6, lane = tid & 63;
  int qc = lane >> 4, ch = lane & 15;
  int r_ = ch & 7;
  int u  = wv*32 + qc*8 + r_;
  bool act = (ch < 8);
  const i32x4* wfp = wfrag + (size_t)(dir*8 + wv)*2048 + lane;
  i32x4 a[32];                         // A-frags a[rt*4+kt] (128 regs)
  #pragma unroll
  for (int i=0;i<32;i++) a[i] = wfp[(size_t)i*64];
  if (tid < 64) ((unsigned long long*)lhB)[tid] = 0ULL;   // zero both buffers
  float c = 0.0f;
  const f16* gxc = gx + (size_t)(b*512)*2048 + dir*1024 + u;
  f16* Hcb = Hc + (size_t)b*512*512 + dir*256 + u;
  const float ISC = 1.0f/(2048.0f*127.0f);
  __syncthreads();
  int s0 = dir ? 511 : 0;
  const f16* gp0 = gxc + (size_t)s0*2048;
  f16 gn0 = gp0[0], gn1 = gp0[256], gn2 = gp0[512], gn3 = gp0[768];
  for (int t=0; t<512; t++){
    int s = dir ? (511-t) : t;
    int cur = t & 1;
    int tn = (t < 511) ? t+1 : 511;
    int sn = dir ? (511 - tn) : tn;
    const f16* gp = gxc + (size_t)sn*2048;
    f16 f0 = gp[0], f1 = gp[256], f2 = gp[512], f3 = gp[768];
    i32x4 hb[4];
    #pragma unroll
    for (int kt=0; kt<4; kt++) hb[kt] = *(const i32x4*)&lhB[cur][kt*64 + qc*16];
    i32x4 ac[8];
    #pragma unroll
    for (int rt=0; rt<8; rt++) ac[rt] = (i32x4){0,0,0,0};
    #pragma unroll
    for (int kt=0; kt<4; kt++){
      #pragma unroll
      for (int rt=0; rt<8; rt++)
        ac[rt] = __builtin_amdgcn_mfma_i32_16x16x64_i8(a[rt*4+kt], hb[kt], ac[rt], 0,0,0);
    }
    i32x4 pv = ac[0];
    #pragma unroll
    for (int rt=1; rt<8; rt++){
      pv[0] = (r_ == rt) ? ac[rt][0] : pv[0];
      pv[1] = (r_ == rt) ? ac[rt][1] : pv[1];
      pv[2] = (r_ == rt) ? ac[rt][2] : pv[2];
      pv[3] = (r_ == rt) ? ac[rt][3] : pv[3];
    }
    float p0 = (float)pv[0]*ISC + (float)gn0;
    float p1 = (float)pv[1]*ISC + (float)gn1;
    float p2 = (float)pv[2]*ISC + (float)gn2;
    float p3 = (float)pv[3]*ISC + (float)gn3;
    float ig = sigm(p0), fg = sigm(p1);
    float gg = tanh_(p2), og = sigm(p3);
    c = fg*c + ig*gg;
    float h = og*tanh_(c);
    if (act){
      Hcb[(size_t)s*512] = (f16)h;
      int q = (int)rintf(h * 127.0f);
      lhB[cur^1][u] = (unsigned char)(signed char)q;
    }
    gn0 = f0; gn1 = f1; gn2 = f2; gn3 = f3;
    bar_lgkm();
  }
}

// ---------- K3: emissions e[m][k] = Hcat[m] . Wproj[k] + b_proj[k]  (wave per row) ----------
__global__ __launch_bounds__(256) void k_emis(const f16* __restrict__ Hc,
                 const f16* __restrict__ Wp, const float* __restrict__ bp,
                 float* __restrict__ e){
  int w = threadIdx.x >> 6, l = threadIdx.x & 63;
  int m = blockIdx.x*4 + w;
  f16x8 hv = *(const f16x8*)(Hc + (size_t)m*512 + l*8);
  u32x4 hu = __builtin_bit_cast(u32x4, hv);
  #pragma unroll
  for (int k=0;k<9;k++){
    f16x8 wv = *(const f16x8*)(Wp + k*512 + l*8);
    u32x4 wu = __builtin_bit_cast(u32x4, wv);
    float p = 0.f;
    #pragma unroll
    for (int q=0;q<4;q++) p = dot2u(hu[q], wu[q], p);
    #pragma unroll
    for (int off=32; off; off>>=1) p += __shfl_xor(p, off);
    if (l == k) e[(size_t)m*9 + k] = p + bp[k];
  }
}

// ---------- K4a: CRF chunk scan (log-semiring 9x9 transfer matrices) ----------
__global__ __launch_bounds__(128) void k_crfscan(const float* __restrict__ e,
                       const int* __restrict__ mask, const float* __restrict__ tr,
                       float* __restrict__ P){
  __shared__ float M[2][81];
  int bid = blockIdx.x;
  int b = bid >> 3, w = bid & 7;
  int t = threadIdx.x;
  bool on = (t < 81);
  int i = on ? (t / 9) : 0;
  int j = on ? (t % 9) : 0;
  float Tcol[9];
  #pragma unroll
  for (int k=0;k<9;k++) Tcol[k] = tr[k*9 + j];
  if (on) M[0][t] = (i==j) ? 0.0f : -1e30f;
  __syncthreads();
  const float* eb = e + (size_t)b*512*9;
  const int* mb = mask + b*512;
  int s_lo = w*64 + 1;
  int s_hi = (s_lo + 64 < 512) ? (s_lo + 64) : 512;
  int cur = 0;
  for (int s = s_lo; s < s_hi; s++){
    if (on){
      int ms = mb[s];
      float ej = eb[(size_t)s*9 + j];
      float v[9];
      #pragma unroll
      for (int k=0;k<9;k++) v[k] = M[cur][i*9+k] + Tcol[k];
      float mx = v[0];
      #pragma unroll
      for (int k=1;k<9;k++) mx = fmaxf(mx, v[k]);
      float ssum = 0.f;
      #pragma unroll
      for (int k=0;k<9;k++) ssum += expf(v[k]-mx);
      float nv = mx + logf(ssum) + ej;
      M[cur^1][t] = (ms != 0) ? nv : M[cur][t];
    }
    cur ^= 1;
    __syncthreads();
  }
  if (on) P[(size_t)bid*81 + t] = M[cur][t];
}

// ---------- K4b: CRF finalize per batch (1 wave) ----------
__global__ void k_crffin(const float* __restrict__ e, const int* __restrict__ tags,
                         const int* __restrict__ mask, const float* __restrict__ st,
                         const float* __restrict__ en, const float* __restrict__ tr,
                         const float* __restrict__ P, float* __restrict__ llh){
  int b = blockIdx.x;
  int l = threadIdx.x;                 // 64 threads
  const float* eb = e + (size_t)b*512*9;
  const int* tb = tags + b*512;
  const int* mb = mask + b*512;
  float nump = 0.f;
  int cnt = 0;
  for (int s = l; s < 512; s += 64){
    int ms = mb[s];
    cnt += (ms != 0) ? 1 : 0;
    if (s >= 1){
      int tg = tb[s], pv = tb[s-1];
      nump += (float)ms * (tr[pv*9+tg] + eb[(size_t)s*9+tg]);
    }
  }
  #pragma unroll
  for (int off=32; off; off>>=1){
    nump += __shfl_xor(nump, off);
    cnt  += __shfl_xor(cnt, off);
  }
  int j = (l < 9) ? l : 0;
  float a = st[j] + eb[j];
  for (int w=0; w<8; w++){
    const float* Pw = P + (size_t)(b*8 + w)*81;
    float v[9];
    #pragma unroll
    for (int i=0;i<9;i++) v[i] = rdlane(a, i) + Pw[i*9 + j];
    float mx = v[0];
    #pragma unroll
    for (int i=1;i<9;i++) mx = fmaxf(mx, v[i]);
    float ssum = 0.f;
    #pragma unroll
    for (int i=0;i<9;i++) ssum += expf(v[i]-mx);
    a = mx + logf(ssum);
  }
  float av[9];
  #pragma unroll
  for (int i=0;i<9;i++) av[i] = rdlane(a, i) + en[i];
  float mx = av[0];
  #pragma unroll
  for (int i=1;i<9;i++) mx = fmaxf(mx, av[i]);
  float ssum = 0.f;
  #pragma unroll
  for (int i=0;i<9;i++) ssum += expf(av[i]-mx);
  float logZ = mx + logf(ssum);
  if (l == 0){
    int t0 = tb[0];
    int lastt = tb[cnt-1];
    llh[b] = (st[t0] + eb[t0] + nump + en[lastt]) - logZ;
  }
}

// ---------- K5: final reduce (wave-parallel) ----------
__global__ void k_red(const float* __restrict__ llh, float* __restrict__ out){
  int l = threadIdx.x;
  float s = llh[l];
  #pragma unroll
  for (int off=32; off; off>>=1) s += __shfl_xor(s, off);
  if (l == 0) out[0] = -s / 64.0f;
}

extern "C" void kernel_launch(void* const* d_in, const int* in_sizes, int n_in,
                              void* d_out, int out_size, void* d_ws, size_t ws_size,
                              hipStream_t stream){
  const float* emb  = (const float*)d_in[0];
  const int*   tags = (const int*)d_in[1];
  const int*   mask = (const int*)d_in[2];
  const float* wihf = (const float*)d_in[3];
  const float* whhf = (const float*)d_in[4];
  const float* bfp  = (const float*)d_in[5];
  const float* wihb = (const float*)d_in[6];
  const float* whhb = (const float*)d_in[7];
  const float* bbp  = (const float*)d_in[8];
  const float* wprj = (const float*)d_in[9];
  const float* bprj = (const float*)d_in[10];
  const float* st   = (const float*)d_in[11];
  const float* en   = (const float*)d_in[12];
  const float* tr   = (const float*)d_in[13];

  char* ws = (char*)d_ws;
  signed char* A8  = (signed char*)(ws + 0);     // 25,165,824 B used of 50 MB slot
  f16*   Hc    = (f16*)(ws + 0);                 // 33,554,432 B — aliases A8 slot
                                                 // (A8 only read by k_gemm8, before k_rnn)
  signed char* W8  = (signed char*)(ws + 50331648);   // 1,572,864 B
  u32x4* Wpack = (u32x4*)(ws + 53477376);        //    524,288 B used
  float* crfP  = (float*)(ws + 54001664);        //    165,888 B (free tail of Wpack slot)
  f16*   Wpj   = (f16*)(ws + 54525952);          //      9,216 B
  f16*   gx    = (f16*)(ws + 54535168);          // 134,217,728 B (plain [m][n])
  float* e     = (float*)(ws + 188752896);       //  1,179,648 B
  float* llh   = (float*)(ws + 189932544);       //        256 B

  hipLaunchKernelGGL(k_cvt8,    dim3(6144), dim3(256), 0, stream, emb, A8, 25165824, 32.0f);
  hipLaunchKernelGGL(k_prep,    dim3(515),  dim3(256), 0, stream, wihf, wihb, wprj,
                     whhf, whhb, W8, Wpj, Wpack);
  hipLaunchKernelGGL(k_gemm8,   dim3(4096), dim3(256), 0, stream, A8, W8, bfp, bbp, gx);
  hipLaunchKernelGGL(k_rnn,     dim3(128),  dim3(512), 0, stream, (const i32x4*)Wpack, gx, Hc);
  hipLaunchKernelGGL(k_emis,    dim3(8192), dim3(256), 0, stream, Hc, Wpj, bprj, e);
  hipLaunchKernelGGL(k_crfscan, dim3(512),  dim3(128), 0, stream, e, mask, tr, crfP);
  hipLaunchKernelGGL(k_crffin,  dim3(64),   dim3(64),  0, stream, e, tags, mask, st, en, tr, crfP, llh);
  hipLaunchKernelGGL(k_red,     dim3(1),    dim3(64),  0, stream, llh, (float*)d_out);
}

// Round 15
// 650.280 us; speedup vs baseline: 1.0154x; 1.0154x over previous
//
#include <hip/hip_runtime.h>

typedef _Float16 f16;
typedef _Float16 f16x2 __attribute__((ext_vector_type(2)));
typedef _Float16 f16x4 __attribute__((ext_vector_type(4)));
typedef _Float16 f16x8 __attribute__((ext_vector_type(8)));
typedef float    f32x4 __attribute__((ext_vector_type(4)));
typedef int      i32x4 __attribute__((ext_vector_type(4)));
typedef unsigned int u32x4 __attribute__((ext_vector_type(4)));

// ---------- helpers ----------
__device__ __forceinline__ float dot2u(unsigned a, unsigned b, float c){
  return __builtin_amdgcn_fdot2(__builtin_bit_cast(f16x2, a),
                                __builtin_bit_cast(f16x2, b), c, false);
}
__device__ __forceinline__ float sigm(float x){ return 1.0f/(1.0f+__expf(-x)); }
__device__ __forceinline__ float tanh_(float x){
  x = fminf(fmaxf(x, -20.f), 20.f);
  return 1.0f - 2.0f/(__expf(2.0f*x)+1.0f);
}
__device__ __forceinline__ float rdlane(float v, int idx){
  return __builtin_bit_cast(float,
           __builtin_amdgcn_readlane(__builtin_bit_cast(int, v), idx));
}

// Barrier that does NOT drain vmcnt (cross-thread traffic is LDS-only).
__device__ __forceinline__ void bar_lgkm(){
  asm volatile("s_waitcnt lgkmcnt(0)\n\ts_barrier" ::: "memory");
}

#if __has_builtin(__builtin_amdgcn_global_load_lds)
#define HAVE_GLL 1
#else
#define HAVE_GLL 0
#endif

__device__ __forceinline__ void quant16(const float* __restrict__ src,
                                        signed char* __restrict__ dst,
                                        int i, float scale){
  u32x4 o;
  #pragma unroll
  for (int q=0;q<4;q++){
    float4 a = *(const float4*)(src + i + q*4);
    int q0 = (int)rintf(a.x*scale); q0 = q0>127?127:(q0<-127?-127:q0);
    int q1 = (int)rintf(a.y*scale); q1 = q1>127?127:(q1<-127?-127:q1);
    int q2 = (int)rintf(a.z*scale); q2 = q2>127?127:(q2<-127?-127:q2);
    int q3 = (int)rintf(a.w*scale); q3 = q3>127?127:(q3<-127?-127:q3);
    o[q] = ((unsigned)(unsigned char)(signed char)q0)
         | (((unsigned)(unsigned char)(signed char)q1) << 8)
         | (((unsigned)(unsigned char)(signed char)q2) << 16)
         | (((unsigned)(unsigned char)(signed char)q3) << 24);
  }
  *(u32x4*)(dst+i) = o;
}

// ---------- K_prep: ALL prep in one launch ----------
// bid 0..6143   : quant emb -> A8 (scale 32)
// 6144..6335    : quant wihf -> W8 (scale 2048)
// 6336..6527    : quant wihb -> W8+786432
// 6528..6530    : wprj fp32 -> f16
// 6531..6658    : W_hh i8 MFMA A-frag pack (gate-interleaved perm, x2048)
__global__ void k_prep(const float* __restrict__ emb, const float* __restrict__ wihf,
                       const float* __restrict__ wihb, const float* __restrict__ wprj,
                       const float* __restrict__ whf, const float* __restrict__ whb,
                       signed char* __restrict__ A8, signed char* __restrict__ W8,
                       f16* __restrict__ Wpj, u32x4* __restrict__ wf){
  int bid = blockIdx.x, tid = threadIdx.x;
  if (bid < 6144){
    int i = (bid*256 + tid)*16;
    if (i < 25165824) quant16(emb, A8, i, 32.0f);
  } else if (bid < 6528){
    const float* src = (bid < 6336) ? wihf : wihb;
    signed char* dst = W8 + ((bid < 6336) ? 0 : 786432);
    int b2 = (bid < 6336) ? bid - 6144 : bid - 6336;
    int i = (b2*256 + tid)*16;
    if (i < 786432) quant16(src, dst, i, 2048.0f);
  } else if (bid < 6531){
    int i = ((bid-6528)*256 + tid)*8;
    if (i >= 4608) return;
    float4 a = *(const float4*)(wprj + i);
    float4 b = *(const float4*)(wprj + i + 4);
    f16x8 o;
    o[0]=(f16)a.x; o[1]=(f16)a.y; o[2]=(f16)a.z; o[3]=(f16)a.w;
    o[4]=(f16)b.x; o[5]=(f16)b.y; o[6]=(f16)b.z; o[7]=(f16)b.w;
    *(f16x8*)(Wpj+i) = o;
  } else {
    int idx = (bid-6531)*256 + tid;    // 0..32767
    int lane = idx & 63;
    int kt   = (idx >> 6) & 3;
    int rt   = (idx >> 8) & 7;
    int wv   = (idx >> 11) & 7;
    int dir  = (idx >> 14) & 1;
    const float* w = dir ? whb : whf;
    int i2 = lane & 15;
    int u  = wv*32 + (i2 >> 2)*8 + rt;
    int g  = i2 & 3;
    int k0 = kt*64 + (lane >> 4)*16;
    const float* row = w + (size_t)(g*256 + u)*256 + k0;
    u32x4 v = {0,0,0,0};
    #pragma unroll
    for (int j=0;j<16;j++){
      int q = (int)rintf(row[j] * 2048.0f);
      q = q > 127 ? 127 : (q < -127 ? -127 : q);
      v[j>>2] |= ((unsigned)(unsigned char)(signed char)q) << ((j&3)*8);
    }
    wf[idx] = v;
  }
}

// ---------- K1: gx = X8 @ W8^T * 1/65536 + bias -> f16  (i8 MFMA 16x16x64) ----------
// r12-proven 2-barrier form (T14 pipelining measured neutral-negative in r14).
// T2 XOR-swizzle both-sides (rule 21): GLL writes linearly, global source col
// pre-swizzled, ds_read applies same XOR.
__global__ __launch_bounds__(256) void k_gemm8(const signed char* __restrict__ A8,
                                               const signed char* __restrict__ B8,
                                               const float* __restrict__ bf_,
                                               const float* __restrict__ bb_,
                                               f16* __restrict__ C){
  __shared__ alignas(16) signed char As[128][128];
  __shared__ alignas(16) signed char Bs[128][128];
  int bid = blockIdx.x;
  int bm = bid >> 4, bn = bid & 15;
  int tid = threadIdx.x;
  int w = tid >> 6, l = tid & 63;
  int wm = w >> 1, wn = w & 1;
  i32x4 acc[4][4] = {};
  const signed char* Agb = A8 + (size_t)(bm*128)*768;
  const signed char* Bgb = B8 + (size_t)(bn*128)*768;
  int fr = l & 15, kg = l >> 4;
  int swzA = (fr & 7) << 4;                      // read-side XOR for A/B frags
#if !HAVE_GLL
  int srow = tid >> 3;
  int scol = (tid & 7)*16;
  int swzW = (srow & 7) << 4;
#endif
  for (int k0 = 0; k0 < 768; k0 += 128){
#if HAVE_GLL
    int colsw = ((l&7)*16) ^ (((l>>3)&7)<<4);    // source col pre-swizzled
    #pragma unroll
    for (int i=0;i<4;i++){
      int row = (w*4+i)*8 + (l>>3);
      __builtin_amdgcn_global_load_lds(
        (const __attribute__((address_space(1))) void*)(Agb + (size_t)row*768 + k0 + colsw),
        (__attribute__((address_space(3))) void*)((char*)&As[0][0] + (w*4+i)*1024),
        16, 0, 0);
      __builtin_amdgcn_global_load_lds(
        (const __attribute__((address_space(1))) void*)(Bgb + (size_t)row*768 + k0 + colsw),
        (__attribute__((address_space(3))) void*)((char*)&Bs[0][0] + (w*4+i)*1024),
        16, 0, 0);
    }
#else
    #pragma unroll
    for (int q=0;q<4;q++){
      int rr = srow + 32*q;
      u32x4 av = *(const u32x4*)(Agb + (size_t)rr*768 + k0 + scol);
      u32x4 bv = *(const u32x4*)(Bgb + (size_t)rr*768 + k0 + scol);
      *(u32x4*)&As[rr][scol ^ swzW] = av;
      *(u32x4*)&Bs[rr][scol ^ swzW] = bv;
    }
#endif
    __syncthreads();
    #pragma unroll
    for (int ks=0; ks<2; ks++){
      i32x4 af[4], bf[4];
      #pragma unroll
      for (int mi=0;mi<4;mi++)
        af[mi] = *(const i32x4*)&As[wm*64+mi*16+fr][(ks*64+kg*16) ^ swzA];
      #pragma unroll
      for (int ni=0;ni<4;ni++)
        bf[ni] = *(const i32x4*)&Bs[wn*64+ni*16+fr][(ks*64+kg*16) ^ swzA];
      #pragma unroll
      for (int mi=0;mi<4;mi++)
        #pragma unroll
        for (int ni=0;ni<4;ni++)
          acc[mi][ni] = __builtin_amdgcn_mfma_i32_16x16x64_i8(af[mi], bf[ni], acc[mi][ni], 0,0,0);
    }
    __syncthreads();
  }
  const float GS = 1.0f/65536.0f;      // 1/(scaleX * scaleW) = 1/(32*2048)
  int fq = l >> 4;
  #pragma unroll
  for (int ni=0;ni<4;ni++){
    int ncol = bn*128 + wn*64 + ni*16 + fr;
    float bv = (ncol < 1024) ? bf_[ncol] : bb_[ncol - 1024];
    #pragma unroll
    for (int mi=0;mi<4;mi++){
      int mrow = bm*128 + wm*64 + mi*16 + fq*4;
      #pragma unroll
      for (int r=0;r<4;r++)
        C[(size_t)(mrow+r)*2048 + ncol] = (f16)((float)acc[mi][ni][r]*GS + bv);
    }
  }
}

// ---------- K2: recurrence. 128 blocks (1 chain each), i8 MFMA 16x16x64 ----------
// (FROZEN — proven at ~521 us)
__global__ __launch_bounds__(512,2) void k_rnn(const i32x4* __restrict__ wfrag,
            const f16* __restrict__ gx, f16* __restrict__ Hc){
  __shared__ alignas(16) unsigned char lhB[2][256];
  int bid = blockIdx.x;                // 0..127
  int b = bid >> 1, dir = bid & 1;
  int tid = threadIdx.x;
  int wv = tid >> 6, lane = tid & 63;
  int qc = lane >> 4, ch = lane & 15;
  int r_ = ch & 7;
  int u  = wv*32 + qc*8 + r_;
  bool act = (ch < 8);
  const i32x4* wfp = wfrag + (size_t)(dir*8 + wv)*2048 + lane;
  i32x4 a[32];                         // A-frags a[rt*4+kt] (128 regs)
  #pragma unroll
  for (int i=0;i<32;i++) a[i] = wfp[(size_t)i*64];
  if (tid < 64) ((unsigned long long*)lhB)[tid] = 0ULL;   // zero both buffers
  float c = 0.0f;
  const f16* gxc = gx + (size_t)(b*512)*2048 + dir*1024 + u;
  f16* Hcb = Hc + (size_t)b*512*512 + dir*256 + u;
  const float ISC = 1.0f/(2048.0f*127.0f);
  __syncthreads();
  int s0 = dir ? 511 : 0;
  const f16* gp0 = gxc + (size_t)s0*2048;
  f16 gn0 = gp0[0], gn1 = gp0[256], gn2 = gp0[512], gn3 = gp0[768];
  for (int t=0; t<512; t++){
    int s = dir ? (511-t) : t;
    int cur = t & 1;
    int tn = (t < 511) ? t+1 : 511;
    int sn = dir ? (511 - tn) : tn;
    const f16* gp = gxc + (size_t)sn*2048;
    f16 f0 = gp[0], f1 = gp[256], f2 = gp[512], f3 = gp[768];
    i32x4 hb[4];
    #pragma unroll
    for (int kt=0; kt<4; kt++) hb[kt] = *(const i32x4*)&lhB[cur][kt*64 + qc*16];
    i32x4 ac[8];
    #pragma unroll
    for (int rt=0; rt<8; rt++) ac[rt] = (i32x4){0,0,0,0};
    #pragma unroll
    for (int kt=0; kt<4; kt++){
      #pragma unroll
      for (int rt=0; rt<8; rt++)
        ac[rt] = __builtin_amdgcn_mfma_i32_16x16x64_i8(a[rt*4+kt], hb[kt], ac[rt], 0,0,0);
    }
    i32x4 pv = ac[0];
    #pragma unroll
    for (int rt=1; rt<8; rt++){
      pv[0] = (r_ == rt) ? ac[rt][0] : pv[0];
      pv[1] = (r_ == rt) ? ac[rt][1] : pv[1];
      pv[2] = (r_ == rt) ? ac[rt][2] : pv[2];
      pv[3] = (r_ == rt) ? ac[rt][3] : pv[3];
    }
    float p0 = (float)pv[0]*ISC + (float)gn0;
    float p1 = (float)pv[1]*ISC + (float)gn1;
    float p2 = (float)pv[2]*ISC + (float)gn2;
    float p3 = (float)pv[3]*ISC + (float)gn3;
    float ig = sigm(p0), fg = sigm(p1);
    float gg = tanh_(p2), og = sigm(p3);
    c = fg*c + ig*gg;
    float h = og*tanh_(c);
    if (act){
      Hcb[(size_t)s*512] = (f16)h;
      int q = (int)rintf(h * 127.0f);
      lhB[cur^1][u] = (unsigned char)(signed char)q;
    }
    gn0 = f0; gn1 = f1; gn2 = f2; gn3 = f3;
    bar_lgkm();
  }
}

// ---------- K3: emissions e[m][k] = Hcat[m] . Wproj[k] + b_proj[k]  (wave per row) ----------
__global__ __launch_bounds__(256) void k_emis(const f16* __restrict__ Hc,
                 const f16* __restrict__ Wp, const float* __restrict__ bp,
                 float* __restrict__ e){
  int w = threadIdx.x >> 6, l = threadIdx.x & 63;
  int m = blockIdx.x*4 + w;
  f16x8 hv = *(const f16x8*)(Hc + (size_t)m*512 + l*8);
  u32x4 hu = __builtin_bit_cast(u32x4, hv);
  #pragma unroll
  for (int k=0;k<9;k++){
    f16x8 wv = *(const f16x8*)(Wp + k*512 + l*8);
    u32x4 wu = __builtin_bit_cast(u32x4, wv);
    float p = 0.f;
    #pragma unroll
    for (int q=0;q<4;q++) p = dot2u(hu[q], wu[q], p);
    #pragma unroll
    for (int off=32; off; off>>=1) p += __shfl_xor(p, off);
    if (l == k) e[(size_t)m*9 + k] = p + bp[k];
  }
}

// ---------- K4a: CRF chunk scan (log-semiring 9x9 transfer matrices) ----------
__global__ __launch_bounds__(128) void k_crfscan(const float* __restrict__ e,
                       const int* __restrict__ mask, const float* __restrict__ tr,
                       float* __restrict__ P){
  __shared__ float M[2][81];
  int bid = blockIdx.x;
  int b = bid >> 3, w = bid & 7;
  int t = threadIdx.x;
  bool on = (t < 81);
  int i = on ? (t / 9) : 0;
  int j = on ? (t % 9) : 0;
  float Tcol[9];
  #pragma unroll
  for (int k=0;k<9;k++) Tcol[k] = tr[k*9 + j];
  if (on) M[0][t] = (i==j) ? 0.0f : -1e30f;
  __syncthreads();
  const float* eb = e + (size_t)b*512*9;
  const int* mb = mask + b*512;
  int s_lo = w*64 + 1;
  int s_hi = (s_lo + 64 < 512) ? (s_lo + 64) : 512;
  int cur = 0;
  for (int s = s_lo; s < s_hi; s++){
    if (on){
      int ms = mb[s];
      float ej = eb[(size_t)s*9 + j];
      float v[9];
      #pragma unroll
      for (int k=0;k<9;k++) v[k] = M[cur][i*9+k] + Tcol[k];
      float mx = v[0];
      #pragma unroll
      for (int k=1;k<9;k++) mx = fmaxf(mx, v[k]);
      float ssum = 0.f;
      #pragma unroll
      for (int k=0;k<9;k++) ssum += expf(v[k]-mx);
      float nv = mx + logf(ssum) + ej;
      M[cur^1][t] = (ms != 0) ? nv : M[cur][t];
    }
    cur ^= 1;
    __syncthreads();
  }
  if (on) P[(size_t)bid*81 + t] = M[cur][t];
}

// ---------- K4b: CRF finalize per batch (1 wave) ----------
__global__ void k_crffin(const float* __restrict__ e, const int* __restrict__ tags,
                         const int* __restrict__ mask, const float* __restrict__ st,
                         const float* __restrict__ en, const float* __restrict__ tr,
                         const float* __restrict__ P, float* __restrict__ llh){
  int b = blockIdx.x;
  int l = threadIdx.x;                 // 64 threads
  const float* eb = e + (size_t)b*512*9;
  const int* tb = tags + b*512;
  const int* mb = mask + b*512;
  float nump = 0.f;
  int cnt = 0;
  for (int s = l; s < 512; s += 64){
    int ms = mb[s];
    cnt += (ms != 0) ? 1 : 0;
    if (s >= 1){
      int tg = tb[s], pv = tb[s-1];
      nump += (float)ms * (tr[pv*9+tg] + eb[(size_t)s*9+tg]);
    }
  }
  #pragma unroll
  for (int off=32; off; off>>=1){
    nump += __shfl_xor(nump, off);
    cnt  += __shfl_xor(cnt, off);
  }
  int j = (l < 9) ? l : 0;
  float a = st[j] + eb[j];
  for (int w=0; w<8; w++){
    const float* Pw = P + (size_t)(b*8 + w)*81;
    float v[9];
    #pragma unroll
    for (int i=0;i<9;i++) v[i] = rdlane(a, i) + Pw[i*9 + j];
    float mx = v[0];
    #pragma unroll
    for (int i=1;i<9;i++) mx = fmaxf(mx, v[i]);
    float ssum = 0.f;
    #pragma unroll
    for (int i=0;i<9;i++) ssum += expf(v[i]-mx);
    a = mx + logf(ssum);
  }
  float av[9];
  #pragma unroll
  for (int i=0;i<9;i++) av[i] = rdlane(a, i) + en[i];
  float mx = av[0];
  #pragma unroll
  for (int i=1;i<9;i++) mx = fmaxf(mx, av[i]);
  float ssum = 0.f;
  #pragma unroll
  for (int i=0;i<9;i++) ssum += expf(av[i]-mx);
  float logZ = mx + logf(ssum);
  if (l == 0){
    int t0 = tb[0];
    int lastt = tb[cnt-1];
    llh[b] = (st[t0] + eb[t0] + nump + en[lastt]) - logZ;
  }
}

// ---------- K5: final reduce (wave-parallel) ----------
__global__ void k_red(const float* __restrict__ llh, float* __restrict__ out){
  int l = threadIdx.x;
  float s = llh[l];
  #pragma unroll
  for (int off=32; off; off>>=1) s += __shfl_xor(s, off);
  if (l == 0) out[0] = -s / 64.0f;
}

extern "C" void kernel_launch(void* const* d_in, const int* in_sizes, int n_in,
                              void* d_out, int out_size, void* d_ws, size_t ws_size,
                              hipStream_t stream){
  const float* emb  = (const float*)d_in[0];
  const int*   tags = (const int*)d_in[1];
  const int*   mask = (const int*)d_in[2];
  const float* wihf = (const float*)d_in[3];
  const float* whhf = (const float*)d_in[4];
  const float* bfp  = (const float*)d_in[5];
  const float* wihb = (const float*)d_in[6];
  const float* whhb = (const float*)d_in[7];
  const float* bbp  = (const float*)d_in[8];
  const float* wprj = (const float*)d_in[9];
  const float* bprj = (const float*)d_in[10];
  const float* st   = (const float*)d_in[11];
  const float* en   = (const float*)d_in[12];
  const float* tr   = (const float*)d_in[13];

  char* ws = (char*)d_ws;
  signed char* A8  = (signed char*)(ws + 0);     // 25,165,824 B used of 50 MB slot
  f16*   Hc    = (f16*)(ws + 0);                 // 33,554,432 B — aliases A8 slot
                                                 // (A8 only read by k_gemm8, before k_rnn)
  signed char* W8  = (signed char*)(ws + 50331648);   // 1,572,864 B
  u32x4* Wpack = (u32x4*)(ws + 53477376);        //    524,288 B used
  float* crfP  = (float*)(ws + 54001664);        //    165,888 B (free tail of Wpack slot)
  f16*   Wpj   = (f16*)(ws + 54525952);          //      9,216 B
  f16*   gx    = (f16*)(ws + 54535168);          // 134,217,728 B (plain [m][n])
  float* e     = (float*)(ws + 188752896);       //  1,179,648 B
  float* llh   = (float*)(ws + 189932544);       //        256 B

  hipLaunchKernelGGL(k_prep,    dim3(6659), dim3(256), 0, stream, emb, wihf, wihb, wprj,
                     whhf, whhb, A8, W8, Wpj, Wpack);
  hipLaunchKernelGGL(k_gemm8,   dim3(4096), dim3(256), 0, stream, A8, W8, bfp, bbp, gx);
  hipLaunchKernelGGL(k_rnn,     dim3(128),  dim3(512), 0, stream, (const i32x4*)Wpack, gx, Hc);
  hipLaunchKernelGGL(k_emis,    dim3(8192), dim3(256), 0, stream, Hc, Wpj, bprj, e);
  hipLaunchKernelGGL(k_crfscan, dim3(512),  dim3(128), 0, stream, e, mask, tr, crfP);
  hipLaunchKernelGGL(k_crffin,  dim3(64),   dim3(64),  0, stream, e, tags, mask, st, en, tr, crfP, llh);
  hipLaunchKernelGGL(k_red,     dim3(1),    dim3(64),  0, stream, llh, (float*)d_out);
}